// Round 1
// baseline (613.295 us; speedup 1.0000x reference)
//
#include <hip/hip_runtime.h>
#include <math.h>

// GATv2 (in_ch=1, edge_dim=1, H=2, C=64) + fc, fully collapsed to rank-1/rank-2 algebra.
//
// ws layout (floats):
//   [0,N)      deg        (atomic)
//   [N,2N)     asum       (atomic)  sum of incoming edge_attr
//   [2N,4N)    den[2n+h]  (atomic)  softmax denominator (no max-sub; logits ~ +-1)
//   [4N,6N)    num[2n+h]  (atomic)  sum exp(logit)*x[src]
//   [6N,8N)    S[2n+h]              per-node per-head weighted source scalar
//   [8N+0..)   A1[128], A2[128], BASE[128], U0[128], U1[128], CONST[128], flag(int)

#define LRELU_A1 0.6f   // leakyrelu(v) = 0.6 v + 0.4 |v|  (slope 0.2)
#define LRELU_A2 0.4f

__global__ void k_detect(const unsigned int* __restrict__ ei, int* __restrict__ flag) {
  if (threadIdx.x == 0 && blockIdx.x == 0) {
    int z = 1;
    for (int i = 0; i < 32; i++) if (ei[2*i + 1] != 0u) { z = 0; break; }
    *flag = z;  // 1 => edge_index stored as int64 (little-endian), 0 => int32
  }
}

__global__ void k_prep(const float* __restrict__ att,
                       const float* __restrict__ b_l, const float* __restrict__ b_r,
                       float* __restrict__ A1, float* __restrict__ A2,
                       float* __restrict__ BASE) {
  int j = threadIdx.x;
  if (j < 128) {
    float a = att[j];
    A1[j] = LRELU_A1 * a;
    A2[j] = LRELU_A2 * a;
    BASE[j] = b_l[j] + b_r[j];
  }
}

#define CH_STEP(comp, ACC, i)                                                      \
  do {                                                                             \
    float v_ = fmaf(xs[i], wl.comp, fmaf(xt[i], wr.comp, fmaf(ae[i], we.comp, bb.comp))); \
    ACC[i] = fmaf(a2.comp, fabsf(v_), fmaf(a1.comp, v_, ACC[i]));                  \
  } while (0)

__global__ __launch_bounds__(256) void k_edge(
    const float* __restrict__ x, const int* __restrict__ ei,
    const float* __restrict__ ea,
    const float* __restrict__ WL, const float* __restrict__ WR,
    const float* __restrict__ WE,
    const float* __restrict__ A1, const float* __restrict__ A2,
    const float* __restrict__ BASE,
    float* __restrict__ deg, float* __restrict__ asum,
    float* __restrict__ den, float* __restrict__ num,
    const int* __restrict__ flagp, int E) {
  int t = blockIdx.x * blockDim.x + threadIdx.x;
  int e0 = t * 4;
  if (e0 >= E) return;
  const bool w64 = (*flagp) != 0;
  int de[4];
  float ae[4], xs[4], xt[4];
  bool ok[4];
#pragma unroll
  for (int i = 0; i < 4; i++) {
    int e = e0 + i;
    ok[i] = (e < E);
    int ee = ok[i] ? e : e0;
    int s_ = w64 ? ei[2 * ee] : ei[ee];
    int d_ = w64 ? ei[2 * (E + ee)] : ei[E + ee];
    de[i] = d_;
    ae[i] = ea[ee];
    xs[i] = x[s_];
    xt[i] = x[d_];
  }
  float acc0[4] = {0.f, 0.f, 0.f, 0.f};
  float acc1[4] = {0.f, 0.f, 0.f, 0.f};
#pragma unroll 4
  for (int jb = 0; jb < 64; jb += 4) {
    float4 wl = *(const float4*)(WL + jb);
    float4 wr = *(const float4*)(WR + jb);
    float4 we = *(const float4*)(WE + jb);
    float4 bb = *(const float4*)(BASE + jb);
    float4 a1 = *(const float4*)(A1 + jb);
    float4 a2 = *(const float4*)(A2 + jb);
#pragma unroll
    for (int i = 0; i < 4; i++) {
      CH_STEP(x, acc0, i); CH_STEP(y, acc0, i); CH_STEP(z, acc0, i); CH_STEP(w, acc0, i);
    }
  }
#pragma unroll 4
  for (int jb = 64; jb < 128; jb += 4) {
    float4 wl = *(const float4*)(WL + jb);
    float4 wr = *(const float4*)(WR + jb);
    float4 we = *(const float4*)(WE + jb);
    float4 bb = *(const float4*)(BASE + jb);
    float4 a1 = *(const float4*)(A1 + jb);
    float4 a2 = *(const float4*)(A2 + jb);
#pragma unroll
    for (int i = 0; i < 4; i++) {
      CH_STEP(x, acc1, i); CH_STEP(y, acc1, i); CH_STEP(z, acc1, i); CH_STEP(w, acc1, i);
    }
  }
#pragma unroll
  for (int i = 0; i < 4; i++) {
    if (!ok[i]) break;  // tail-only invalidity
    float eh0 = __expf(acc0[i]);
    float eh1 = __expf(acc1[i]);
    int d_ = de[i];
    atomicAdd(&deg[d_], 1.0f);
    atomicAdd(&asum[d_], ae[i]);
    atomicAdd(&den[2 * d_ + 0], eh0);
    atomicAdd(&num[2 * d_ + 0], eh0 * xs[i]);
    atomicAdd(&den[2 * d_ + 1], eh1);
    atomicAdd(&num[2 * d_ + 1], eh1 * xs[i]);
  }
}

__global__ __launch_bounds__(256) void k_node(
    const float* __restrict__ x,
    const float* __restrict__ WL, const float* __restrict__ WR,
    const float* __restrict__ WE,
    const float* __restrict__ A1, const float* __restrict__ A2,
    const float* __restrict__ BASE,
    const float* __restrict__ deg, const float* __restrict__ asum,
    const float* __restrict__ den, const float* __restrict__ num,
    float* __restrict__ S, int N) {
  int n = blockIdx.x * blockDim.x + threadIdx.x;
  if (n >= N) return;
  float xn = x[n];
  float am = asum[n] / fmaxf(deg[n], 1.0f);
  float acc0 = 0.f, acc1 = 0.f;
#pragma unroll 4
  for (int jb = 0; jb < 64; jb += 4) {
    float4 wl = *(const float4*)(WL + jb);
    float4 wr = *(const float4*)(WR + jb);
    float4 we = *(const float4*)(WE + jb);
    float4 bb = *(const float4*)(BASE + jb);
    float4 a1 = *(const float4*)(A1 + jb);
    float4 a2 = *(const float4*)(A2 + jb);
    float v;
    v = fmaf(xn, wl.x + wr.x, fmaf(am, we.x, bb.x)); acc0 = fmaf(a2.x, fabsf(v), fmaf(a1.x, v, acc0));
    v = fmaf(xn, wl.y + wr.y, fmaf(am, we.y, bb.y)); acc0 = fmaf(a2.y, fabsf(v), fmaf(a1.y, v, acc0));
    v = fmaf(xn, wl.z + wr.z, fmaf(am, we.z, bb.z)); acc0 = fmaf(a2.z, fabsf(v), fmaf(a1.z, v, acc0));
    v = fmaf(xn, wl.w + wr.w, fmaf(am, we.w, bb.w)); acc0 = fmaf(a2.w, fabsf(v), fmaf(a1.w, v, acc0));
  }
#pragma unroll 4
  for (int jb = 64; jb < 128; jb += 4) {
    float4 wl = *(const float4*)(WL + jb);
    float4 wr = *(const float4*)(WR + jb);
    float4 we = *(const float4*)(WE + jb);
    float4 bb = *(const float4*)(BASE + jb);
    float4 a1 = *(const float4*)(A1 + jb);
    float4 a2 = *(const float4*)(A2 + jb);
    float v;
    v = fmaf(xn, wl.x + wr.x, fmaf(am, we.x, bb.x)); acc1 = fmaf(a2.x, fabsf(v), fmaf(a1.x, v, acc1));
    v = fmaf(xn, wl.y + wr.y, fmaf(am, we.y, bb.y)); acc1 = fmaf(a2.y, fabsf(v), fmaf(a1.y, v, acc1));
    v = fmaf(xn, wl.z + wr.z, fmaf(am, we.z, bb.z)); acc1 = fmaf(a2.z, fabsf(v), fmaf(a1.z, v, acc1));
    v = fmaf(xn, wl.w + wr.w, fmaf(am, we.w, bb.w)); acc1 = fmaf(a2.w, fabsf(v), fmaf(a1.w, v, acc1));
  }
  float e0 = __expf(acc0), e1 = __expf(acc1);
  float2 dn = *(const float2*)(den + 2 * n);
  float2 nm = *(const float2*)(num + 2 * n);
  float2 sv;
  sv.x = (nm.x + e0 * xn) / (dn.x + e0);
  sv.y = (nm.y + e1 * xn) / (dn.y + e1);
  *(float2*)(S + 2 * n) = sv;
}

__global__ void k_const(const float* __restrict__ W_l,
                        const float* __restrict__ b_l,
                        const float* __restrict__ bias_out,
                        const float* __restrict__ W_fc,
                        const float* __restrict__ b_fc,
                        const float* __restrict__ S, const int* __restrict__ tgtp,
                        float* __restrict__ U0, float* __restrict__ U1,
                        float* __restrict__ CONST) {
  int k = threadIdx.x;
  if (k >= 128) return;
  const float* wrow = W_fc + k * 256;
  int T = *tgtp;  // low word works for both int32 and int64 little-endian
  float S0 = S[2 * T], S1 = S[2 * T + 1];
  float u0 = 0.f, u1 = 0.f, cst = b_fc[k];
  for (int c = 0; c < 64; c++) {
    u0 = fmaf(W_l[c], wrow[c], u0);
    u1 = fmaf(W_l[64 + c], wrow[64 + c], u1);
  }
  for (int j = 0; j < 128; j++) {
    float gb = b_l[j] + bias_out[j];
    float tg = fmaf((j < 64) ? S0 : S1, W_l[j], gb);
    cst = fmaf(gb, wrow[j], cst);
    cst = fmaf(tg, wrow[128 + j], cst);
  }
  U0[k] = u0; U1[k] = u1; CONST[k] = cst;
}

__global__ __launch_bounds__(256) void k_out(
    const float* __restrict__ S, const float* __restrict__ U0,
    const float* __restrict__ U1, const float* __restrict__ CONST,
    float* __restrict__ out, int N) {
  int g = blockIdx.x * blockDim.x + threadIdx.x;
  if (g >= N * 32) return;
  int n = g >> 5;
  int kq = (g & 31) * 4;
  float2 s = *(const float2*)(S + 2 * n);
  float4 u0 = *(const float4*)(U0 + kq);
  float4 u1 = *(const float4*)(U1 + kq);
  float4 c = *(const float4*)(CONST + kq);
  float4 o;
  o.x = fmaf(s.x, u0.x, fmaf(s.y, u1.x, c.x));
  o.y = fmaf(s.x, u0.y, fmaf(s.y, u1.y, c.y));
  o.z = fmaf(s.x, u0.z, fmaf(s.y, u1.z, c.z));
  o.w = fmaf(s.x, u0.w, fmaf(s.y, u1.w, c.w));
  *(float4*)(out + n * 128 + kq) = o;
}

extern "C" void kernel_launch(void* const* d_in, const int* in_sizes, int n_in,
                              void* d_out, int out_size, void* d_ws, size_t ws_size,
                              hipStream_t stream) {
  const float* x        = (const float*)d_in[0];
  const int*   ei       = (const int*)d_in[1];
  const float* ea       = (const float*)d_in[2];
  const int*   tgt      = (const int*)d_in[3];
  const float* W_l      = (const float*)d_in[4];
  const float* b_l      = (const float*)d_in[5];
  const float* W_r      = (const float*)d_in[6];
  const float* b_r      = (const float*)d_in[7];
  const float* W_e      = (const float*)d_in[8];
  const float* att      = (const float*)d_in[9];
  const float* bias_out = (const float*)d_in[10];
  const float* W_fc     = (const float*)d_in[11];
  const float* b_fc     = (const float*)d_in[12];

  const int N = in_sizes[0];
  const int E = in_sizes[2];

  float* ws   = (float*)d_ws;
  float* deg  = ws;
  float* asum = ws + (size_t)N;
  float* den  = ws + (size_t)2 * N;
  float* num  = ws + (size_t)4 * N;
  float* S    = ws + (size_t)6 * N;
  float* A1   = ws + (size_t)8 * N;
  float* A2   = A1 + 128;
  float* BASE = A1 + 256;
  float* U0   = A1 + 384;
  float* U1   = A1 + 512;
  float* CST  = A1 + 640;
  int*   flag = (int*)(A1 + 768);

  hipMemsetAsync(ws, 0, sizeof(float) * (size_t)6 * N, stream);
  k_detect<<<1, 64, 0, stream>>>((const unsigned int*)ei, flag);
  k_prep<<<1, 128, 0, stream>>>(att, b_l, b_r, A1, A2, BASE);

  int nt = (E + 3) / 4;
  k_edge<<<(nt + 255) / 256, 256, 0, stream>>>(x, ei, ea, W_l, W_r, W_e, A1, A2,
                                               BASE, deg, asum, den, num, flag, E);
  k_node<<<(N + 255) / 256, 256, 0, stream>>>(x, W_l, W_r, W_e, A1, A2, BASE, deg,
                                              asum, den, num, S, N);
  k_const<<<1, 128, 0, stream>>>(W_l, b_l, bias_out, W_fc, b_fc, S, tgt, U0, U1, CST);
  k_out<<<(N * 32 + 255) / 256, 256, 0, stream>>>(S, U0, U1, CST, (float*)d_out, N);
}

// Round 2
// 258.266 us; speedup vs baseline: 2.3747x; 2.3747x over previous
//
#include <hip/hip_runtime.h>
#include <math.h>

// GATv2 (in_ch=1, edge_dim=1, H=2, C=64) + fc, collapsed to rank-1/rank-2 algebra.
//
// Round 2: replace 6 float fabric-atomics/edge with 1 returning int atomic/edge
// (bucket slot claim) + plain float4 payload store; per-node reduce kernel.
//
// ws layout:
//   [0, N)            int   cnt[n]     (atomic slot cursor == in-degree)
//   [N, 9N)           float acc[n*8]   overflow accumulators: {-, asum, den0, num0, den1, num1, -, -}
//   [9N, 11N)         float S[2n+h]
//   [11N, 11N+1024)   consts: A1[128],A2[128],BASE[128],U0[128],U1[128],CST[128],flag,...
//   [11N+1024, ...)   float4 bucket[n*STRIDE + slot] payload (exp0, exp1, x_src, edge_attr)

#define LRELU_A1 0.6f   // leakyrelu(v) = 0.6 v + 0.4 |v|  (slope 0.2)
#define LRELU_A2 0.4f

__global__ void k_detect(const unsigned int* __restrict__ ei, int* __restrict__ flag) {
  if (threadIdx.x == 0 && blockIdx.x == 0) {
    int z = 1;
    for (int i = 0; i < 32; i++) if (ei[2*i + 1] != 0u) { z = 0; break; }
    *flag = z;  // 1 => edge_index is int64 (little-endian), 0 => int32
  }
}

__global__ void k_prep(const float* __restrict__ att,
                       const float* __restrict__ b_l, const float* __restrict__ b_r,
                       float* __restrict__ A1, float* __restrict__ A2,
                       float* __restrict__ BASE) {
  int j = threadIdx.x;
  if (j < 128) {
    float a = att[j];
    A1[j] = LRELU_A1 * a;
    A2[j] = LRELU_A2 * a;
    BASE[j] = b_l[j] + b_r[j];
  }
}

#define CH_STEP(comp, ACC, i)                                                      \
  do {                                                                             \
    float v_ = fmaf(xs[i], wl.comp, fmaf(xt[i], wr.comp, fmaf(ae[i], we.comp, bb.comp))); \
    ACC[i] = fmaf(a2.comp, fabsf(v_), fmaf(a1.comp, v_, ACC[i]));                  \
  } while (0)

__global__ __launch_bounds__(256) void k_edge(
    const float* __restrict__ x, const int* __restrict__ ei,
    const float* __restrict__ ea,
    const float* __restrict__ WL, const float* __restrict__ WR,
    const float* __restrict__ WE,
    const float* __restrict__ A1, const float* __restrict__ A2,
    const float* __restrict__ BASE,
    int* __restrict__ cnt, float* __restrict__ acc,
    float4* __restrict__ bucket, int stride,
    const int* __restrict__ flagp, int E) {
  int t = blockIdx.x * blockDim.x + threadIdx.x;
  int e0i = t * 4;
  if (e0i >= E) return;
  const bool w64 = (*flagp) != 0;
  int de[4];
  float ae[4], xs[4], xt[4];
  bool ok[4];
#pragma unroll
  for (int i = 0; i < 4; i++) {
    int e = e0i + i;
    ok[i] = (e < E);
    int ee = ok[i] ? e : e0i;
    int s_ = w64 ? ei[2 * ee] : ei[ee];
    int d_ = w64 ? ei[2 * (E + ee)] : ei[E + ee];
    de[i] = d_;
    ae[i] = ea[ee];
    xs[i] = x[s_];
    xt[i] = x[d_];
  }
  float acc0[4] = {0.f, 0.f, 0.f, 0.f};
  float acc1[4] = {0.f, 0.f, 0.f, 0.f};
#pragma unroll 4
  for (int jb = 0; jb < 64; jb += 4) {
    float4 wl = *(const float4*)(WL + jb);
    float4 wr = *(const float4*)(WR + jb);
    float4 we = *(const float4*)(WE + jb);
    float4 bb = *(const float4*)(BASE + jb);
    float4 a1 = *(const float4*)(A1 + jb);
    float4 a2 = *(const float4*)(A2 + jb);
#pragma unroll
    for (int i = 0; i < 4; i++) {
      CH_STEP(x, acc0, i); CH_STEP(y, acc0, i); CH_STEP(z, acc0, i); CH_STEP(w, acc0, i);
    }
  }
#pragma unroll 4
  for (int jb = 64; jb < 128; jb += 4) {
    float4 wl = *(const float4*)(WL + jb);
    float4 wr = *(const float4*)(WR + jb);
    float4 we = *(const float4*)(WE + jb);
    float4 bb = *(const float4*)(BASE + jb);
    float4 a1 = *(const float4*)(A1 + jb);
    float4 a2 = *(const float4*)(A2 + jb);
#pragma unroll
    for (int i = 0; i < 4; i++) {
      CH_STEP(x, acc1, i); CH_STEP(y, acc1, i); CH_STEP(z, acc1, i); CH_STEP(w, acc1, i);
    }
  }
  // claim slots first (lets the 4 returning atomics overlap)
  int pos[4];
#pragma unroll
  for (int i = 0; i < 4; i++) {
    pos[i] = ok[i] ? atomicAdd(&cnt[de[i]], 1) : 0;
  }
#pragma unroll
  for (int i = 0; i < 4; i++) {
    if (!ok[i]) continue;
    float eh0 = __expf(acc0[i]);
    float eh1 = __expf(acc1[i]);
    int d_ = de[i];
    if (pos[i] < stride) {
      bucket[(size_t)d_ * stride + pos[i]] = make_float4(eh0, eh1, xs[i], ae[i]);
    } else {  // rare overflow: old atomic path (deg comes from cnt, so 5 adds)
      float* a = acc + (size_t)d_ * 8;
      atomicAdd(a + 1, ae[i]);
      atomicAdd(a + 2, eh0);
      atomicAdd(a + 3, eh0 * xs[i]);
      atomicAdd(a + 4, eh1);
      atomicAdd(a + 5, eh1 * xs[i]);
    }
  }
}

__global__ __launch_bounds__(256) void k_node(
    const float* __restrict__ x,
    const float* __restrict__ WL, const float* __restrict__ WR,
    const float* __restrict__ WE,
    const float* __restrict__ A1, const float* __restrict__ A2,
    const float* __restrict__ BASE,
    const int* __restrict__ cnt, const float* __restrict__ acc,
    const float4* __restrict__ bucket, int stride,
    float* __restrict__ S, int N) {
  int n = blockIdx.x * blockDim.x + threadIdx.x;
  if (n >= N) return;
  int c = cnt[n];
  const float* a = acc + (size_t)n * 8;
  float asum = a[1];
  float den0 = a[2], num0 = a[3], den1 = a[4], num1 = a[5];
  int m = min(c, stride);
  const float4* b = bucket + (size_t)n * stride;
  for (int i = 0; i < m; i++) {
    float4 p = b[i];
    den0 += p.x; num0 += p.x * p.z;
    den1 += p.y; num1 += p.y * p.z;
    asum += p.w;
  }
  float xn = x[n];
  float am = asum / fmaxf((float)c, 1.0f);
  float acc0 = 0.f, acc1 = 0.f;
#pragma unroll 4
  for (int jb = 0; jb < 64; jb += 4) {
    float4 wl = *(const float4*)(WL + jb);
    float4 wr = *(const float4*)(WR + jb);
    float4 we = *(const float4*)(WE + jb);
    float4 bb = *(const float4*)(BASE + jb);
    float4 a1 = *(const float4*)(A1 + jb);
    float4 a2 = *(const float4*)(A2 + jb);
    float v;
    v = fmaf(xn, wl.x + wr.x, fmaf(am, we.x, bb.x)); acc0 = fmaf(a2.x, fabsf(v), fmaf(a1.x, v, acc0));
    v = fmaf(xn, wl.y + wr.y, fmaf(am, we.y, bb.y)); acc0 = fmaf(a2.y, fabsf(v), fmaf(a1.y, v, acc0));
    v = fmaf(xn, wl.z + wr.z, fmaf(am, we.z, bb.z)); acc0 = fmaf(a2.z, fabsf(v), fmaf(a1.z, v, acc0));
    v = fmaf(xn, wl.w + wr.w, fmaf(am, we.w, bb.w)); acc0 = fmaf(a2.w, fabsf(v), fmaf(a1.w, v, acc0));
  }
#pragma unroll 4
  for (int jb = 64; jb < 128; jb += 4) {
    float4 wl = *(const float4*)(WL + jb);
    float4 wr = *(const float4*)(WR + jb);
    float4 we = *(const float4*)(WE + jb);
    float4 bb = *(const float4*)(BASE + jb);
    float4 a1 = *(const float4*)(A1 + jb);
    float4 a2 = *(const float4*)(A2 + jb);
    float v;
    v = fmaf(xn, wl.x + wr.x, fmaf(am, we.x, bb.x)); acc1 = fmaf(a2.x, fabsf(v), fmaf(a1.x, v, acc1));
    v = fmaf(xn, wl.y + wr.y, fmaf(am, we.y, bb.y)); acc1 = fmaf(a2.y, fabsf(v), fmaf(a1.y, v, acc1));
    v = fmaf(xn, wl.z + wr.z, fmaf(am, we.z, bb.z)); acc1 = fmaf(a2.z, fabsf(v), fmaf(a1.z, v, acc1));
    v = fmaf(xn, wl.w + wr.w, fmaf(am, we.w, bb.w)); acc1 = fmaf(a2.w, fabsf(v), fmaf(a1.w, v, acc1));
  }
  float e0 = __expf(acc0), e1 = __expf(acc1);
  float2 sv;
  sv.x = (num0 + e0 * xn) / (den0 + e0);
  sv.y = (num1 + e1 * xn) / (den1 + e1);
  *(float2*)(S + 2 * n) = sv;
}

__global__ void k_const(const float* __restrict__ W_l,
                        const float* __restrict__ b_l,
                        const float* __restrict__ bias_out,
                        const float* __restrict__ W_fc,
                        const float* __restrict__ b_fc,
                        const float* __restrict__ S, const int* __restrict__ tgtp,
                        float* __restrict__ U0, float* __restrict__ U1,
                        float* __restrict__ CONST) {
  int k = threadIdx.x;
  if (k >= 128) return;
  const float* wrow = W_fc + k * 256;
  int T = *tgtp;  // low word works for both int32 and int64 little-endian
  float S0 = S[2 * T], S1 = S[2 * T + 1];
  float u0 = 0.f, u1 = 0.f, cst = b_fc[k];
  for (int c = 0; c < 64; c++) {
    u0 = fmaf(W_l[c], wrow[c], u0);
    u1 = fmaf(W_l[64 + c], wrow[64 + c], u1);
  }
  for (int j = 0; j < 128; j++) {
    float gb = b_l[j] + bias_out[j];
    float tg = fmaf((j < 64) ? S0 : S1, W_l[j], gb);
    cst = fmaf(gb, wrow[j], cst);
    cst = fmaf(tg, wrow[128 + j], cst);
  }
  U0[k] = u0; U1[k] = u1; CONST[k] = cst;
}

__global__ __launch_bounds__(256) void k_out(
    const float* __restrict__ S, const float* __restrict__ U0,
    const float* __restrict__ U1, const float* __restrict__ CONST,
    float* __restrict__ out, int N) {
  int g = blockIdx.x * blockDim.x + threadIdx.x;
  if (g >= N * 32) return;
  int n = g >> 5;
  int kq = (g & 31) * 4;
  float2 s = *(const float2*)(S + 2 * n);
  float4 u0 = *(const float4*)(U0 + kq);
  float4 u1 = *(const float4*)(U1 + kq);
  float4 c = *(const float4*)(CONST + kq);
  float4 o;
  o.x = fmaf(s.x, u0.x, fmaf(s.y, u1.x, c.x));
  o.y = fmaf(s.x, u0.y, fmaf(s.y, u1.y, c.y));
  o.z = fmaf(s.x, u0.z, fmaf(s.y, u1.z, c.z));
  o.w = fmaf(s.x, u0.w, fmaf(s.y, u1.w, c.w));
  *(float4*)(out + n * 128 + kq) = o;
}

extern "C" void kernel_launch(void* const* d_in, const int* in_sizes, int n_in,
                              void* d_out, int out_size, void* d_ws, size_t ws_size,
                              hipStream_t stream) {
  const float* x        = (const float*)d_in[0];
  const int*   ei       = (const int*)d_in[1];
  const float* ea       = (const float*)d_in[2];
  const int*   tgt      = (const int*)d_in[3];
  const float* W_l      = (const float*)d_in[4];
  const float* b_l      = (const float*)d_in[5];
  const float* W_r      = (const float*)d_in[6];
  const float* b_r      = (const float*)d_in[7];
  const float* W_e      = (const float*)d_in[8];
  const float* att      = (const float*)d_in[9];
  const float* bias_out = (const float*)d_in[10];
  const float* W_fc     = (const float*)d_in[11];
  const float* b_fc     = (const float*)d_in[12];

  const int N = in_sizes[0];
  const int E = in_sizes[2];

  float* ws   = (float*)d_ws;
  int*   cnt  = (int*)ws;                       // N ints
  float* acc  = ws + (size_t)N;                 // 8N floats
  float* S    = ws + (size_t)9 * N;             // 2N floats
  float* A1   = ws + (size_t)11 * N;            // consts region (1024 floats)
  float* A2   = A1 + 128;
  float* BASE = A1 + 256;
  float* U0   = A1 + 384;
  float* U1   = A1 + 512;
  float* CST  = A1 + 640;
  int*   flag = (int*)(A1 + 768);
  size_t base_bytes = ((size_t)11 * N + 1024) * sizeof(float);
  float4* bucket = (float4*)((char*)d_ws + base_bytes);

  int stride = 0;
  if (ws_size > base_bytes) {
    size_t s = (ws_size - base_bytes) / ((size_t)N * sizeof(float4));
    stride = (int)(s > 64 ? 64 : s);
  }

  hipMemsetAsync(ws, 0, sizeof(float) * (size_t)9 * N, stream);  // cnt + acc
  k_detect<<<1, 64, 0, stream>>>((const unsigned int*)ei, flag);
  k_prep<<<1, 128, 0, stream>>>(att, b_l, b_r, A1, A2, BASE);

  int nt = (E + 3) / 4;
  k_edge<<<(nt + 255) / 256, 256, 0, stream>>>(x, ei, ea, W_l, W_r, W_e, A1, A2,
                                               BASE, cnt, acc, bucket, stride, flag, E);
  k_node<<<(N + 255) / 256, 256, 0, stream>>>(x, W_l, W_r, W_e, A1, A2, BASE, cnt,
                                              acc, bucket, stride, S, N);
  k_const<<<1, 128, 0, stream>>>(W_l, b_l, bias_out, W_fc, b_fc, S, tgt, U0, U1, CST);
  k_out<<<(N * 32 + 255) / 256, 256, 0, stream>>>(S, U0, U1, CST, (float*)d_out, N);
}